// Round 5
// baseline (77.429 us; speedup 1.0000x reference)
//
#include <hip/hip_runtime.h>
#include <math.h>

#define NRAD   12
#define NSPH   16
#define NTYPE  3
#define NATOM  1024
#define MAXNBR 64
#define RCUT   3.6f

// padded LDS strides (coprime to 32 banks -> conflict-free)
#define RSTR   13   // nbR row stride
#define YSTR   17   // nbY row stride
#define CSTR   17   // cbuf row stride (per n)

#define NPAIR  144  // 12 n * 12 q

struct SoapConsts {
    float norm[NRAD];
    float inv2sig2[NRAD];      // 0.5 / sigma^2
    float sinv[NRAD * NRAD];   // S^{-1/2}
};

// ---------------------------------------------------------------------------
// Host-side constant computation (captured into the graph as by-value kernel
// arguments — zero device cost at replay; no device memory, no extra kernel).
// ---------------------------------------------------------------------------
static void compute_consts(SoapConsts* C) {
    // G[t] = Gamma(t/2), t in [2, 25]
    double G[26];
    G[2] = 1.0;
    G[3] = 0.88622692545275801364908374167057259139877;  // Gamma(1.5)
    for (int t = 4; t < 26; ++t) G[t] = (0.5 * t - 1.0) * G[t - 2];

    double sigma[NRAD], norm[NRAD];
    for (int n = 0; n < NRAD; ++n) {
        double sq = sqrt((double)n);
        if (sq < 1.0) sq = 1.0;
        sigma[n] = 3.6 * sq / 12.0;
        norm[n]  = 1.0 / sqrt(0.5 * G[2 * n + 3] * pow(sigma[n], 2.0 * n + 3.0));
    }

    double S[NRAD][NRAD];
    for (int i = 0; i < NRAD; ++i)
        for (int j = 0; j < NRAD; ++j) {
            double c = 0.5 / (sigma[i] * sigma[i]) + 0.5 / (sigma[j] * sigma[j]);
            double e = 0.5 * (i + j + 3.0);
            S[i][j]  = norm[i] * norm[j] * 0.5 * G[i + j + 3] * pow(c, -e);
        }

    // Cyclic Jacobi eigendecomposition (double). S is 12x12 SPD.
    double A[NRAD][NRAD], V[NRAD][NRAD];
    for (int i = 0; i < NRAD; ++i)
        for (int j = 0; j < NRAD; ++j) {
            A[i][j] = S[i][j];
            V[i][j] = (i == j) ? 1.0 : 0.0;
        }
    for (int sweep = 0; sweep < 60; ++sweep) {
        double off = 0.0;
        for (int p = 0; p < NRAD - 1; ++p)
            for (int q = p + 1; q < NRAD; ++q) off += A[p][q] * A[p][q];
        if (off < 1e-26) break;
        for (int p = 0; p < NRAD - 1; ++p) {
            for (int q = p + 1; q < NRAD; ++q) {
                double apq = A[p][q];
                if (fabs(apq) < 1e-300) continue;
                double tau = (A[q][q] - A[p][p]) / (2.0 * apq);
                double tt  = ((tau >= 0.0) ? 1.0 : -1.0) / (fabs(tau) + sqrt(1.0 + tau * tau));
                double cc  = 1.0 / sqrt(1.0 + tt * tt);
                double ss  = tt * cc;
                for (int k = 0; k < NRAD; ++k) {
                    double akp = A[k][p], akq = A[k][q];
                    A[k][p] = cc * akp - ss * akq;
                    A[k][q] = ss * akp + cc * akq;
                }
                for (int k = 0; k < NRAD; ++k) {
                    double apk = A[p][k], aqk = A[q][k];
                    A[p][k] = cc * apk - ss * aqk;
                    A[q][k] = ss * apk + cc * aqk;
                }
                for (int k = 0; k < NRAD; ++k) {
                    double vkp = V[k][p], vkq = V[k][q];
                    V[k][p] = cc * vkp - ss * vkq;
                    V[k][q] = ss * vkp + cc * vkq;
                }
            }
        }
    }
    double wisr[NRAD];
    for (int k = 0; k < NRAD; ++k) wisr[k] = 1.0 / sqrt(A[k][k]);
    for (int i = 0; i < NRAD; ++i)
        for (int j = 0; j < NRAD; ++j) {
            double s = 0.0;
            for (int k = 0; k < NRAD; ++k) s += V[i][k] * wisr[k] * V[j][k];
            C->sinv[i * NRAD + j] = (float)s;
        }
    for (int n = 0; n < NRAD; ++n) {
        C->norm[n]     = (float)norm[n];
        C->inv2sig2[n] = (float)(0.5 / (sigma[n] * sigma[n]));
    }
}

// ---------------------------------------------------------------------------
// One 64-lane wave (= one block) per atom. 4096 blocks, ~10 neighbors/atom.
//   A: ballot-compacted neighbor scan (exact: cutoff_fn is exactly 0 at r>=RC)
//   B: per-neighbor radial basis (SINV folded) + real spherical harmonics l<=3
//   C: accumulate c[3 types][12 rad][16 sph] into LDS
//   D: pair-major contraction with W (144 (n,q) pairs over 64 lanes x 3)
// ---------------------------------------------------------------------------
__global__ __launch_bounds__(64) void soap_kernel(
    const float* __restrict__ positions,  // (4,1024,3)
    const int*   __restrict__ species,    // (4,1024)
    const float* __restrict__ W,          // (3456)
    const float* __restrict__ bias,       // (1)
    float*       __restrict__ out,        // (4096)
    SoapConsts C)
{
    const int atom = blockIdx.x;
    const int b    = atom >> 10;
    const int i    = atom & (NATOM - 1);
    const int lane = threadIdx.x;

    const float* pos = positions + b * NATOM * 3;
    const float xi = pos[3 * i], yi = pos[3 * i + 1], zi = pos[3 * i + 2];

    __shared__ int   nbIdx[MAXNBR];
    __shared__ float nbR[MAXNBR][RSTR];
    __shared__ float nbY[MAXNBR][YSTR];
    __shared__ int   nbSp[MAXNBR];
    __shared__ float cbuf[NTYPE][NRAD * CSTR];

    // ---- Phase A: ballot-compacted neighbor scan -------------------------
    int nNbr = 0;
    const float rc2 = RCUT * RCUT;
    for (int base = 0; base < NATOM; base += 64) {
        int j = base + lane;
        float dx = xi - pos[3 * j];
        float dy = yi - pos[3 * j + 1];
        float dz = zi - pos[3 * j + 2];
        float d2 = dx * dx + dy * dy + dz * dz;
        bool pred = (j != i) && (d2 < rc2);
        unsigned long long m = __ballot(pred);
        if (pred) {
            int slot = nNbr + __popcll(m & ((1ull << lane) - 1ull));
            if (slot < MAXNBR) nbIdx[slot] = j;
        }
        nNbr += __popcll(m);
    }
    if (nNbr > MAXNBR) nNbr = MAXNBR;   // mean ~10, P(>64) ~ 0
    __syncthreads();

    // ---- Phase B: per-neighbor radial basis + spherical harmonics --------
    if (lane < nNbr) {
        int j = nbIdx[lane];
        float dx = xi - pos[3 * j];
        float dy = yi - pos[3 * j + 1];
        float dz = zi - pos[3 * j + 2];
        float d2 = dx * dx + dy * dy + dz * dz;
        float d  = sqrtf(d2);
        float inv = 1.0f / d;
        float ux = dx * inv, uy = dy * inv, uz = dz * inv;

        // smooth cutoff
        float t = (d - (RCUT - 0.3f)) * (1.0f / 0.3f);
        t = fminf(fmaxf(t, 0.0f), 1.0f);
        float w = 0.5f * (1.0f + cosf(3.14159265358979323846f * t));

        // g[n] = norm * r^n * exp(-0.5 r^2/sig^2), cutoff weight folded in
        float g[NRAD];
        float rp = 1.0f;
        #pragma unroll
        for (int n = 0; n < NRAD; ++n) {
            g[n] = C.norm[n] * rp * expf(-d2 * C.inv2sig2[n]) * w;
            rp *= d;
        }
        #pragma unroll
        for (int mm = 0; mm < NRAD; ++mm) {
            float s = 0.0f;
            #pragma unroll
            for (int n = 0; n < NRAD; ++n) s += g[n] * C.sinv[n * NRAD + mm];
            nbR[lane][mm] = s;
        }

        float x2 = ux * ux, y2 = uy * uy, z2 = uz * uz;
        nbY[lane][0]  = 0.28209479177387814f;
        nbY[lane][1]  = 0.4886025119029199f * uy;
        nbY[lane][2]  = 0.4886025119029199f * uz;
        nbY[lane][3]  = 0.4886025119029199f * ux;
        nbY[lane][4]  = 1.0925484305920792f * ux * uy;
        nbY[lane][5]  = 1.0925484305920792f * uy * uz;
        nbY[lane][6]  = 0.31539156525252005f * (3.0f * z2 - 1.0f);
        nbY[lane][7]  = 1.0925484305920792f * ux * uz;
        nbY[lane][8]  = 0.5462742152960396f * (x2 - y2);
        nbY[lane][9]  = 0.5900435899266435f * uy * (3.0f * x2 - y2);
        nbY[lane][10] = 2.890611442640554f * ux * uy * uz;
        nbY[lane][11] = 0.4570457994644658f * uy * (5.0f * z2 - 1.0f);
        nbY[lane][12] = 0.3731763325901154f * uz * (5.0f * z2 - 3.0f);
        nbY[lane][13] = 0.4570457994644658f * ux * (5.0f * z2 - 1.0f);
        nbY[lane][14] = 1.445305721320277f * uz * (x2 - y2);
        nbY[lane][15] = 0.5900435899266435f * ux * (3.0f * x2 - y2);
        nbSp[lane] = species[b * NATOM + j];
    }
    __syncthreads();

    // ---- Phase C: accumulate c[3][12][16]; lane owns 3 (m,k) slots -------
    float a0[3], a1_[3], a2_[3];
    int mI[3], kI[3];
    #pragma unroll
    for (int t = 0; t < 3; ++t) {
        a0[t] = a1_[t] = a2_[t] = 0.0f;
        int mk = lane + t * 64;
        mI[t] = mk >> 4;
        kI[t] = mk & 15;
    }
    for (int j = 0; j < nNbr; ++j) {
        int sp = nbSp[j];
        #pragma unroll
        for (int t = 0; t < 3; ++t) {
            float v = nbR[j][mI[t]] * nbY[j][kI[t]];
            a0[t]  += (sp == 0) ? v : 0.0f;
            a1_[t] += (sp == 1) ? v : 0.0f;
            a2_[t] += (sp == 2) ? v : 0.0f;
        }
    }
    #pragma unroll
    for (int t = 0; t < 3; ++t) {
        cbuf[0][mI[t] * CSTR + kI[t]] = a0[t];
        cbuf[1][mI[t] * CSTR + kI[t]] = a1_[t];
        cbuf[2][mI[t] * CSTR + kI[t]] = a2_[t];
    }
    __syncthreads();

    // ---- Phase D: pair-major contraction ---------------------------------
    // out = b + sum_{p,n,q,l} W[p*576+n*48+q*4+l] * FACT_p * LS_l * <c1,c2>_l
    // p,l are unrolled constants -> FACT*LS folds to a literal; the W address
    // is (p*576+l) + n*48 + q*4 (L1-resident 13.8 KB table).
    float partial = 0.0f;
    for (int t = 0; t < 3; ++t) {
        int pi  = lane + (t << 6);                 // 0..191; 144 real pairs
        bool act = (pi < NPAIR);
        int piC = act ? pi : 0;
        int n = piC / 12;
        int q = piC - 12 * n;
        int nb = n * CSTR;
        int qb = q * CSTR;
        const float* wrow = W + n * 48 + q * 4;
        float acc = 0.0f;
        #pragma unroll
        for (int l = 0; l < 4; ++l) {
            const int st  = l * l;
            const int cnt = 2 * l + 1;
            float c1v[3][7], c2v[3][7];
            #pragma unroll
            for (int s = 0; s < 3; ++s) {
                #pragma unroll
                for (int m = 0; m < 7; ++m) {
                    if (m < cnt) {
                        c1v[s][m] = cbuf[s][nb + st + m];
                        c2v[s][m] = cbuf[s][qb + st + m];
                    }
                }
            }
            const float ls = (l == 0) ? 1.0f
                           : (l == 1) ? 0.57735026918962576f
                           : (l == 2) ? 0.44721359549995794f
                           :            0.37796447300922722f;
            #pragma unroll
            for (int p = 0; p < 6; ++p) {
                const int s1 = (p < 3) ? 0 : ((p < 5) ? 1 : 2);
                const int s2 = (p < 3) ? p : ((p < 5) ? (p - 2) : 2);
                const float fact = (s1 != s2) ? 1.41421356237309515f : 1.0f;
                float s = 0.0f;
                #pragma unroll
                for (int m = 0; m < 7; ++m)
                    if (m < cnt) s += c1v[s1][m] * c2v[s2][m];
                acc += wrow[p * 576 + l] * (fact * ls) * s;
            }
        }
        partial += act ? acc : 0.0f;
    }

    #pragma unroll
    for (int off = 32; off > 0; off >>= 1)
        partial += __shfl_down(partial, off, 64);
    if (lane == 0) out[atom] = partial + bias[0];
}

extern "C" void kernel_launch(void* const* d_in, const int* in_sizes, int n_in,
                              void* d_out, int out_size, void* d_ws, size_t ws_size,
                              hipStream_t stream) {
    const float* positions = (const float*)d_in[0];   // (4,1024,3) f32
    const int*   species   = (const int*)d_in[1];     // (4,1024)   i32
    const float* W         = (const float*)d_in[2];   // (3456)     f32
    const float* bias      = (const float*)d_in[3];   // (1)        f32
    float*       out       = (float*)d_out;           // (4096,1)   f32

    SoapConsts C;
    compute_consts(&C);

    int nAtoms = in_sizes[0] / 3;                      // 4096
    soap_kernel<<<nAtoms, 64, 0, stream>>>(positions, species, W, bias, out, C);
}

// Round 7
// 75.727 us; speedup vs baseline: 1.0225x; 1.0225x over previous
//
#include <hip/hip_runtime.h>
#include <math.h>

#define NRAD   12
#define NSPH   16
#define NTYPE  3
#define NATOM  1024
#define MAXNBR 64
#define RCUT   3.6f

// padded LDS strides
#define RSTR   13   // nbR row stride (coprime to 32 -> conflict-free b32)
#define YSTR   17   // nbY row stride (coprime to 32 -> conflict-free b32)
#define CSTR   20   // cbuf row stride: 80B = 16B-aligned for ds_read_b128;
                    // row-start bank (20r mod 32) has period 8 -> <=2-way
                    // aliasing across 12 rows (free per m136)

#define NPAIR  144  // 12 n * 12 q

#define SQRT2F 1.41421356237309515f
#define LS1    0.57735026918962576f   // 1/sqrt(3)
#define LS2    0.44721359549995794f   // 1/sqrt(5)
#define LS3    0.37796447300922722f   // 1/sqrt(7)

struct SoapConsts {
    float norm[NRAD];
    float inv2sig2[NRAD];      // 0.5 / sigma^2
    float sinv[NRAD * NRAD];   // S^{-1/2}
};

// ---------------------------------------------------------------------------
// Host-side constant computation (captured into the graph as by-value kernel
// arguments — zero device cost at replay; no device memory, no extra kernel).
// ---------------------------------------------------------------------------
static void compute_consts(SoapConsts* C) {
    // G[t] = Gamma(t/2), t in [2, 25]
    double G[26];
    G[2] = 1.0;
    G[3] = 0.88622692545275801364908374167057259139877;  // Gamma(1.5)
    for (int t = 4; t < 26; ++t) G[t] = (0.5 * t - 1.0) * G[t - 2];

    double sigma[NRAD], norm[NRAD];
    for (int n = 0; n < NRAD; ++n) {
        double sq = sqrt((double)n);
        if (sq < 1.0) sq = 1.0;
        sigma[n] = 3.6 * sq / 12.0;
        norm[n]  = 1.0 / sqrt(0.5 * G[2 * n + 3] * pow(sigma[n], 2.0 * n + 3.0));
    }

    double S[NRAD][NRAD];
    for (int i = 0; i < NRAD; ++i)
        for (int j = 0; j < NRAD; ++j) {
            double c = 0.5 / (sigma[i] * sigma[i]) + 0.5 / (sigma[j] * sigma[j]);
            double e = 0.5 * (i + j + 3.0);
            S[i][j]  = norm[i] * norm[j] * 0.5 * G[i + j + 3] * pow(c, -e);
        }

    // Cyclic Jacobi eigendecomposition (double). S is 12x12 SPD.
    double A[NRAD][NRAD], V[NRAD][NRAD];
    for (int i = 0; i < NRAD; ++i)
        for (int j = 0; j < NRAD; ++j) {
            A[i][j] = S[i][j];
            V[i][j] = (i == j) ? 1.0 : 0.0;
        }
    for (int sweep = 0; sweep < 60; ++sweep) {
        double off = 0.0;
        for (int p = 0; p < NRAD - 1; ++p)
            for (int q = p + 1; q < NRAD; ++q) off += A[p][q] * A[p][q];
        if (off < 1e-26) break;
        for (int p = 0; p < NRAD - 1; ++p) {
            for (int q = p + 1; q < NRAD; ++q) {
                double apq = A[p][q];
                if (fabs(apq) < 1e-300) continue;
                double tau = (A[q][q] - A[p][p]) / (2.0 * apq);
                double tt  = ((tau >= 0.0) ? 1.0 : -1.0) / (fabs(tau) + sqrt(1.0 + tau * tau));
                double cc  = 1.0 / sqrt(1.0 + tt * tt);
                double ss  = tt * cc;
                for (int k = 0; k < NRAD; ++k) {
                    double akp = A[k][p], akq = A[k][q];
                    A[k][p] = cc * akp - ss * akq;
                    A[k][q] = ss * akp + cc * akq;
                }
                for (int k = 0; k < NRAD; ++k) {
                    double apk = A[p][k], aqk = A[q][k];
                    A[p][k] = cc * apk - ss * aqk;
                    A[q][k] = ss * apk + cc * aqk;
                }
                for (int k = 0; k < NRAD; ++k) {
                    double vkp = V[k][p], vkq = V[k][q];
                    V[k][p] = cc * vkp - ss * vkq;
                    V[k][q] = ss * vkp + cc * vkq;
                }
            }
        }
    }
    double wisr[NRAD];
    for (int k = 0; k < NRAD; ++k) wisr[k] = 1.0 / sqrt(A[k][k]);
    for (int i = 0; i < NRAD; ++i)
        for (int j = 0; j < NRAD; ++j) {
            double s = 0.0;
            for (int k = 0; k < NRAD; ++k) s += V[i][k] * wisr[k] * V[j][k];
            C->sinv[i * NRAD + j] = (float)s;
        }
    for (int n = 0; n < NRAD; ++n) {
        C->norm[n]     = (float)norm[n];
        C->inv2sig2[n] = (float)(0.5 / (sigma[n] * sigma[n]));
    }
}

// Load one 16-float cbuf row (4 x ds_read_b128) into registers.
__device__ __forceinline__ void ldrow(const float* __restrict__ row, float* r) {
    const float4* p = reinterpret_cast<const float4*>(row);
    float4 a = p[0], b = p[1], c = p[2], d = p[3];
    r[0]=a.x;  r[1]=a.y;  r[2]=a.z;  r[3]=a.w;
    r[4]=b.x;  r[5]=b.y;  r[6]=b.z;  r[7]=b.w;
    r[8]=c.x;  r[9]=c.y;  r[10]=c.z; r[11]=c.w;
    r[12]=d.x; r[13]=d.y; r[14]=d.z; r[15]=d.w;
}

// All-l contribution of one species pair: w4 holds W[p,n,q,l=0..3].
__device__ __forceinline__ float dot4l(const float* c1, const float* c2,
                                       float4 w4, float fact) {
    float d0 = c1[0]*c2[0];
    float d1 = c1[1]*c2[1] + c1[2]*c2[2] + c1[3]*c2[3];
    float d2 = c1[4]*c2[4] + c1[5]*c2[5] + c1[6]*c2[6] + c1[7]*c2[7]
             + c1[8]*c2[8];
    float d3 = c1[9]*c2[9] + c1[10]*c2[10] + c1[11]*c2[11] + c1[12]*c2[12]
             + c1[13]*c2[13] + c1[14]*c2[14] + c1[15]*c2[15];
    return fact * (w4.x * d0 + (LS1 * w4.y) * d1
                 + (LS2 * w4.z) * d2 + (LS3 * w4.w) * d3);
}

// ---------------------------------------------------------------------------
// One 64-lane wave (= one block) per atom. 4096 blocks, ~10 neighbors/atom.
//   A: ballot-compacted neighbor scan (exact: cutoff_fn is exactly 0 at r>=RC)
//   B: per-neighbor radial basis (SINV folded) + real spherical harmonics l<=3
//   C: accumulate c[3 types][12 rad][16 sph] into LDS
//   D: pair-major contraction, register-blocked ds_read_b128 row loads
// ---------------------------------------------------------------------------
__global__ __launch_bounds__(64) void soap_kernel(
    const float* __restrict__ positions,  // (4,1024,3)
    const int*   __restrict__ species,    // (4,1024)
    const float* __restrict__ W,          // (3456)
    const float* __restrict__ bias,       // (1)
    float*       __restrict__ out,        // (4096)
    SoapConsts C)
{
    const int atom = blockIdx.x;
    const int b    = atom >> 10;
    const int i    = atom & (NATOM - 1);
    const int lane = threadIdx.x;

    const float* pos = positions + b * NATOM * 3;
    const float xi = pos[3 * i], yi = pos[3 * i + 1], zi = pos[3 * i + 2];

    __shared__ int   nbIdx[MAXNBR];
    __shared__ float nbR[MAXNBR][RSTR];
    __shared__ float nbY[MAXNBR][YSTR];
    __shared__ int   nbSp[MAXNBR];
    __shared__ float cbuf[NTYPE][NRAD * CSTR];   // rows 16B-aligned (80B)

    // ---- Phase A: ballot-compacted neighbor scan -------------------------
    int nNbr = 0;
    const float rc2 = RCUT * RCUT;
    for (int base = 0; base < NATOM; base += 64) {
        int j = base + lane;
        float dx = xi - pos[3 * j];
        float dy = yi - pos[3 * j + 1];
        float dz = zi - pos[3 * j + 2];
        float d2 = dx * dx + dy * dy + dz * dz;
        bool pred = (j != i) && (d2 < rc2);
        unsigned long long m = __ballot(pred);
        if (pred) {
            int slot = nNbr + __popcll(m & ((1ull << lane) - 1ull));
            if (slot < MAXNBR) nbIdx[slot] = j;
        }
        nNbr += __popcll(m);
    }
    if (nNbr > MAXNBR) nNbr = MAXNBR;   // mean ~10, P(>64) ~ 0
    __syncthreads();

    // ---- Phase B: per-neighbor radial basis + spherical harmonics --------
    if (lane < nNbr) {
        int j = nbIdx[lane];
        float dx = xi - pos[3 * j];
        float dy = yi - pos[3 * j + 1];
        float dz = zi - pos[3 * j + 2];
        float d2 = dx * dx + dy * dy + dz * dz;
        float d  = sqrtf(d2);
        float inv = 1.0f / d;
        float ux = dx * inv, uy = dy * inv, uz = dz * inv;

        // smooth cutoff
        float t = (d - (RCUT - 0.3f)) * (1.0f / 0.3f);
        t = fminf(fmaxf(t, 0.0f), 1.0f);
        float w = 0.5f * (1.0f + cosf(3.14159265358979323846f * t));

        // g[n] = norm * r^n * exp(-0.5 r^2/sig^2), cutoff weight folded in
        float g[NRAD];
        float rp = 1.0f;
        #pragma unroll
        for (int n = 0; n < NRAD; ++n) {
            g[n] = C.norm[n] * rp * expf(-d2 * C.inv2sig2[n]) * w;
            rp *= d;
        }
        #pragma unroll
        for (int mm = 0; mm < NRAD; ++mm) {
            float s = 0.0f;
            #pragma unroll
            for (int n = 0; n < NRAD; ++n) s += g[n] * C.sinv[n * NRAD + mm];
            nbR[lane][mm] = s;
        }

        float x2 = ux * ux, y2 = uy * uy, z2 = uz * uz;
        nbY[lane][0]  = 0.28209479177387814f;
        nbY[lane][1]  = 0.4886025119029199f * uy;
        nbY[lane][2]  = 0.4886025119029199f * uz;
        nbY[lane][3]  = 0.4886025119029199f * ux;
        nbY[lane][4]  = 1.0925484305920792f * ux * uy;
        nbY[lane][5]  = 1.0925484305920792f * uy * uz;
        nbY[lane][6]  = 0.31539156525252005f * (3.0f * z2 - 1.0f);
        nbY[lane][7]  = 1.0925484305920792f * ux * uz;
        nbY[lane][8]  = 0.5462742152960396f * (x2 - y2);
        nbY[lane][9]  = 0.5900435899266435f * uy * (3.0f * x2 - y2);
        nbY[lane][10] = 2.890611442640554f * ux * uy * uz;
        nbY[lane][11] = 0.4570457994644658f * uy * (5.0f * z2 - 1.0f);
        nbY[lane][12] = 0.3731763325901154f * uz * (5.0f * z2 - 3.0f);
        nbY[lane][13] = 0.4570457994644658f * ux * (5.0f * z2 - 1.0f);
        nbY[lane][14] = 1.445305721320277f * uz * (x2 - y2);
        nbY[lane][15] = 0.5900435899266435f * ux * (3.0f * x2 - y2);
        nbSp[lane] = species[b * NATOM + j];
    }
    __syncthreads();

    // ---- Phase C: accumulate c[3][12][16]; lane owns 3 (m,k) slots -------
    float a0[3], a1_[3], a2_[3];
    int mI[3], kI[3];
    #pragma unroll
    for (int t = 0; t < 3; ++t) {
        a0[t] = a1_[t] = a2_[t] = 0.0f;
        int mk = lane + t * 64;
        mI[t] = mk >> 4;
        kI[t] = mk & 15;
    }
    for (int j = 0; j < nNbr; ++j) {
        int sp = nbSp[j];
        #pragma unroll
        for (int t = 0; t < 3; ++t) {
            float v = nbR[j][mI[t]] * nbY[j][kI[t]];
            a0[t]  += (sp == 0) ? v : 0.0f;
            a1_[t] += (sp == 1) ? v : 0.0f;
            a2_[t] += (sp == 2) ? v : 0.0f;
        }
    }
    #pragma unroll
    for (int t = 0; t < 3; ++t) {
        cbuf[0][mI[t] * CSTR + kI[t]] = a0[t];
        cbuf[1][mI[t] * CSTR + kI[t]] = a1_[t];
        cbuf[2][mI[t] * CSTR + kI[t]] = a2_[t];
    }
    __syncthreads();

    // ---- Phase D: pair-major contraction, b128 row loads -----------------
    // out = b + sum_{p,n,q,l} W[p*576+n*48+q*4+l] * FACT_p * LS_l * <c1,c2>_l
    // Lane owns (n,q): reads its q-row (3 species) + n-row (3 species) ONCE
    // as 4x float4 each; all l-slices come from registers. W's 4 l-values
    // are contiguous -> one dwordx4 gather per species pair.
    float partial = 0.0f;
    for (int t = 0; t < 3; ++t) {
        int pi  = lane + (t << 6);                 // 0..191; 144 real pairs
        bool act = (pi < NPAIR);
        int piC = act ? pi : 0;
        int n = piC / 12;
        int q = piC - 12 * n;

        float cq0[16], cq1[16], cq2[16], cn_[16];
        ldrow(&cbuf[0][q * CSTR], cq0);
        ldrow(&cbuf[1][q * CSTR], cq1);
        ldrow(&cbuf[2][q * CSTR], cq2);

        const float* wbase = W + n * 48 + q * 4;   // 16B-aligned
        float acc = 0.0f;

        ldrow(&cbuf[0][n * CSTR], cn_);            // s1 = 0
        acc += dot4l(cn_, cq0, *reinterpret_cast<const float4*>(wbase + 0 * 576), 1.0f);
        acc += dot4l(cn_, cq1, *reinterpret_cast<const float4*>(wbase + 1 * 576), SQRT2F);
        acc += dot4l(cn_, cq2, *reinterpret_cast<const float4*>(wbase + 2 * 576), SQRT2F);

        ldrow(&cbuf[1][n * CSTR], cn_);            // s1 = 1
        acc += dot4l(cn_, cq1, *reinterpret_cast<const float4*>(wbase + 3 * 576), 1.0f);
        acc += dot4l(cn_, cq2, *reinterpret_cast<const float4*>(wbase + 4 * 576), SQRT2F);

        ldrow(&cbuf[2][n * CSTR], cn_);            // s1 = 2
        acc += dot4l(cn_, cq2, *reinterpret_cast<const float4*>(wbase + 5 * 576), 1.0f);

        partial += act ? acc : 0.0f;
    }

    #pragma unroll
    for (int off = 32; off > 0; off >>= 1)
        partial += __shfl_down(partial, off, 64);
    if (lane == 0) out[atom] = partial + bias[0];
}

extern "C" void kernel_launch(void* const* d_in, const int* in_sizes, int n_in,
                              void* d_out, int out_size, void* d_ws, size_t ws_size,
                              hipStream_t stream) {
    const float* positions = (const float*)d_in[0];   // (4,1024,3) f32
    const int*   species   = (const int*)d_in[1];     // (4,1024)   i32
    const float* W         = (const float*)d_in[2];   // (3456)     f32
    const float* bias      = (const float*)d_in[3];   // (1)        f32
    float*       out       = (float*)d_out;           // (4096,1)   f32

    SoapConsts C;
    compute_consts(&C);

    int nAtoms = in_sizes[0] / 3;                      // 4096
    soap_kernel<<<nAtoms, 64, 0, stream>>>(positions, species, W, bias, out, C);
}